// Round 2
// baseline (16.565 us; speedup 1.0000x reference)
//
#include <hip/hip_runtime.h>
#include <hip/hip_bf16.h>

// AdaptiveCLPLLoss:
//   B=512, C=100000, K=10, HEAD=2000, S=100, LOGIT_CLIP=20
//   Only head cols, candidate cols, and sampled tail cols of logits are read
//   (~4.3 MB of the 205 MB tensor).
// NOTE: harness passes integer inputs as int32 (NOT int64) — cast to const int*.

#define HEAD_SIZE 2000
#define LOGIT_CLIP 20.0f
#define NCAND 10
#define NSAMP 100
#define BLOCK 256

__device__ __forceinline__ float clipf(float x) {
    return fminf(fmaxf(x, -LOGIT_CLIP), LOGIT_CLIP);
}

// numerically stable softplus: log(1+exp(x)) = max(x,0) + log1p(exp(-|x|))
__device__ __forceinline__ float softplus_f(float x) {
    return fmaxf(x, 0.0f) + log1pf(expf(-fabsf(x)));
}

// block reduce (sum); valid in thread 0. BLOCK=256 -> 4 waves of 64.
__device__ __forceinline__ float block_reduce_sum(float v) {
    #pragma unroll
    for (int off = 32; off > 0; off >>= 1)
        v += __shfl_down(v, off, 64);
    __shared__ float s_part[BLOCK / 64];
    const int lane = threadIdx.x & 63;
    const int wid  = threadIdx.x >> 6;
    if (lane == 0) s_part[wid] = v;
    __syncthreads();
    if (threadIdx.x == 0) {
        v = 0.0f;
        #pragma unroll
        for (int w = 0; w < BLOCK / 64; ++w) v += s_part[w];
    }
    return v;
}

template <bool USE_ATOMIC>
__global__ __launch_bounds__(BLOCK)
void clpl_row_kernel(const float* __restrict__ logits,
                     const int* __restrict__ cand,
                     const int* __restrict__ sidx,
                     float* __restrict__ row_out,   // per-row partials (!USE_ATOMIC) or scalar out (USE_ATOMIC)
                     int C, float tail_scale, float inv_B) {
    const int b = blockIdx.x;
    const float* row = logits + (size_t)b * (size_t)C;

    __shared__ int sc[NCAND];
    if (threadIdx.x < NCAND)
        sc[threadIdx.x] = cand[(size_t)b * NCAND + threadIdx.x];
    __syncthreads();

    float local = 0.0f;

    // term2 (head sum part): sum_{j<HEAD} softplus(clip(x_j))
    for (int j = threadIdx.x; j < HEAD_SIZE; j += BLOCK) {
        local += softplus_f(clipf(row[j]));
    }

    // term3: sampled tail, excluding candidate columns
    for (int s = threadIdx.x; s < NSAMP; s += BLOCK) {
        const int col = HEAD_SIZE + sidx[s];
        bool is_cand = false;
        #pragma unroll
        for (int k = 0; k < NCAND; ++k) {
            if (sc[k] == col) is_cand = true;   // col >= HEAD_SIZE > 0, invalid (<0) never matches
        }
        if (!is_cand) {
            local += softplus_f(clipf(row[col])) * tail_scale;
        }
    }

    // thread 0: dedup candidates (y_mask semantics), term1, and subtract
    // softplus at distinct candidate cols inside the head (1 - head_mask).
    if (threadIdx.x == 0) {
        float csum = 0.0f;
        int   card = 0;
        #pragma unroll
        for (int k = 0; k < NCAND; ++k) {
            const int c = sc[k];
            if (c < 0 || c >= C) continue;       // invalid / safety
            bool dup = false;
            #pragma unroll
            for (int j = 0; j < NCAND; ++j) {
                if (j < k && sc[j] == c) dup = true;
            }
            if (dup) continue;                   // already counted (scat>0 dedups)
            const float x = clipf(row[c]);
            csum += x;
            card += 1;
            if (c < HEAD_SIZE) {
                local -= softplus_f(x);          // head_mask removes it from term2
            }
        }
        const float avg = csum / (float)(card > 0 ? card : 1);
        local += softplus_f(-avg);               // term1 = psi_neg(avg)
    }

    const float total = block_reduce_sum(local);
    if (threadIdx.x == 0) {
        if (USE_ATOMIC) atomicAdd(row_out, total * inv_B);
        else            row_out[b] = total;
    }
}

__global__ __launch_bounds__(BLOCK)
void clpl_reduce_kernel(const float* __restrict__ row_out, float* __restrict__ out, int B) {
    float v = 0.0f;
    for (int i = threadIdx.x; i < B; i += BLOCK) v += row_out[i];
    v = block_reduce_sum(v);
    if (threadIdx.x == 0) out[0] = v / (float)B;
}

extern "C" void kernel_launch(void* const* d_in, const int* in_sizes, int n_in,
                              void* d_out, int out_size, void* d_ws, size_t ws_size,
                              hipStream_t stream) {
    const float* logits = (const float*)d_in[0];
    const int*   cand   = (const int*)d_in[1];   // int64 in reference -> int32 on device
    const int*   sidx   = (const int*)d_in[2];
    float* out = (float*)d_out;

    const int C = 100000;
    const int B = in_sizes[0] / C;                     // 512
    const int tail_size = C - HEAD_SIZE;               // 98000
    const float tail_scale = (float)tail_size / (float)NSAMP;  // 980
    const float inv_B = 1.0f / (float)B;

    if (ws_size >= (size_t)B * sizeof(float)) {
        // deterministic two-stage reduction through workspace
        float* row_out = (float*)d_ws;
        clpl_row_kernel<false><<<B, BLOCK, 0, stream>>>(logits, cand, sidx, row_out,
                                                        C, tail_scale, inv_B);
        clpl_reduce_kernel<<<1, BLOCK, 0, stream>>>(row_out, out, B);
    } else {
        // fallback: atomics into d_out (memset is graph-capture legal)
        hipMemsetAsync(out, 0, sizeof(float), stream);
        clpl_row_kernel<true><<<B, BLOCK, 0, stream>>>(logits, cand, sidx, out,
                                                       C, tail_scale, inv_B);
    }
}